// Round 6
// baseline (248.710 us; speedup 1.0000x reference)
//
#include <hip/hip_runtime.h>

// IntrospectiveAttention on MI355X (gfx950).
// The growing KV cache is dead code (mask = -inf past L); each layer is plain
// causal attention over its own fresh q/k/v. Pipeline:
//   0) cvt_k:     fp32 -> bf16 pre-convert of x/Wq/Wk/Wv/Wo
//   1) gemmqkv_k: FUSED q/k/v projections (r14): one block computes the same
//                 128x128 output region for Wq, Wk AND Wv of one layer --
//                 X-staging amortized 3x (per BK=32 step: 8 gload_lds buy
//                 48 MFMA/wave vs 16/4 unfused; r13 showed the 2-barrier
//                 skeleton is sync-ratio-bound, not latency-bound: BK=32
//                 dbuf issue-early was neutral). 384 blocks, 64 KB LDS,
//                 2 blocks/CU, all co-resident. XCD-chunked swizzle.
//                 Epilogues: q rope*(SCALE*log2e), k rope, v LDS-transpose.
//   2) attn_k:    flash attention, BQ=64, complementary-qt pairing, no-max
//                 exp2 softmax, row sums via ones-MFMA, swizzled K/V dbuf,
//                 XCD-chunked swizzle (8 blocks share one 512 KB KV head)
//   3) combine_k: rmsnorm*lw sum + alpha*x + final rmsnorm -> bf16 xn
//   4) wo_k:      xn @ Wo^T -> fp32 d_out (r13 BK=32 dbuf structure)

#define B_  2
#define L_  1024
#define E_  1024
#define H_  16
#define NL_ 3
#define D_  64

typedef __bf16 bf16_t;
typedef __bf16 bf16x8 __attribute__((ext_vector_type(8)));
typedef __bf16 bf16x4 __attribute__((ext_vector_type(4)));
typedef float  f32x4  __attribute__((ext_vector_type(4)));

#define NEG_INF (-__builtin_inff())

typedef const __attribute__((address_space(1))) void* gas_ptr;
typedef __attribute__((address_space(3))) void* las_ptr;

// async global->LDS, 16B per lane; HW dest = wave-uniform base + lane*16
#define GLD_LDS16(gp, lp) \
  __builtin_amdgcn_global_load_lds((gas_ptr)(gp), (las_ptr)(lp), 16, 0, 0)

// ---------------------------------------------------------------------------
// fp32 -> bf16 convert: segs = Wq/Wk/Wv (3,145,728 ea), Wo (1,048,576),
// x (2,097,152). grid (3072, 5) x 256, 4 elems/thread.
// ---------------------------------------------------------------------------
__global__ __launch_bounds__(256) void cvt_k(
    const float* __restrict__ s0, const float* __restrict__ s1,
    const float* __restrict__ s2, const float* __restrict__ s3,
    const float* __restrict__ s4, bf16_t* __restrict__ d0,
    bf16_t* __restrict__ d1, bf16_t* __restrict__ d2, bf16_t* __restrict__ d3,
    bf16_t* __restrict__ d4)
{
  const int seg = blockIdx.y;
  const float* s;
  bf16_t* d;
  int n;
  if (seg == 0)      { s = s0; d = d0; n = 3145728; }
  else if (seg == 1) { s = s1; d = d1; n = 3145728; }
  else if (seg == 2) { s = s2; d = d2; n = 3145728; }
  else if (seg == 3) { s = s3; d = d3; n = 1048576; }
  else               { s = s4; d = d4; n = 2097152; }
  const int i = (blockIdx.x * 256 + threadIdx.x) * 4;
  if (i < n) {
    const float4 v = *(const float4*)(s + i);
    bf16x4 o;
    o[0] = (bf16_t)v.x; o[1] = (bf16_t)v.y; o[2] = (bf16_t)v.z; o[3] = (bf16_t)v.w;
    *(bf16x4*)(d + i) = o;
  }
}

// ---------------------------------------------------------------------------
// Fused QKV GEMM: for one layer il, one 128-row X panel, one 128-col panel,
// compute q = X Wq^T, k = X Wk^T, v = X Wv^T simultaneously (shared X tile).
// BK=32 double-buffered global_load_lds staging, XOR swizzle on 16 B groups:
//   LDS[row][g] = Global[row][g ^ ((row>>1)&3)]   (verified r13)
// Per buffer (32 KB): X[128][32] @ 0, W0 @ 4096, W1 @ 8192, W2 @ 12288 elems.
// Loop: stage(next) -> compute(cur: 48 MFMA/wave) -> barrier.
// Epilogues: q/k rope (register, partner d^32 = acc[.][ni^2]); v two-pass
// LDS transpose -> VT[il][b][h][d][l].
// Grid (16, 24): bys = colTile + 8*il. XCD-chunked swizzle (384%8==0).
// ---------------------------------------------------------------------------
__global__ __launch_bounds__(256) void gemmqkv_k(
    const bf16_t* __restrict__ X, const bf16_t* __restrict__ W0,
    const bf16_t* __restrict__ W1, const bf16_t* __restrict__ W2,
    const float* __restrict__ cosb, const float* __restrict__ sinb,
    bf16_t* __restrict__ qk, bf16_t* __restrict__ vt)
{
  __shared__ bf16_t smem[32768];  // 64 KB: 2 bufs x (X + 3 W) x 8 KB
  const int tid = threadIdx.x;
  const int lane = tid & 63;
  const int w = tid >> 6;
  const int q4 = lane >> 4, l15 = lane & 15;
  const int row0swz = (l15 >> 1) & 3;

  // XCD-chunked block swizzle: 384 blocks, chunk 48
  const int flat0 = blockIdx.y * 16 + blockIdx.x;
  const int nf = (flat0 & 7) * 48 + (flat0 >> 3);
  const int bxs = nf & 15;
  const int bys = nf >> 4;           // 0..23
  const int row0 = bxs * 128;
  const int il = bys >> 3;           // layer
  const int colTile = bys & 7;
  const int col0 = colTile * 128;

  const bf16_t* Wq = W0 + (size_t)il * E_ * E_;
  const bf16_t* Wk = W1 + (size_t)il * E_ * E_;
  const bf16_t* Wv = W2 + (size_t)il * E_ * E_;

  const int rA = (w & 1) * 64;   // wave's row sub-tile
  const int cB = (w >> 1) * 64;  // wave's col sub-tile

  // staging geometry: row = slab*64 + tid>>2, LDS group tid&3,
  // global group = (tid&3) ^ ((row>>1)&3) = (tid&3) ^ ((tid>>3)&3)
  const int srow = tid >> 2;
  const int sgcol = (((tid & 3) ^ ((tid >> 3) & 3)) << 3);

  f32x4 acc[3][4][4] = {};

  const size_t xrow = (size_t)(row0 + srow) * E_ + sgcol;
  const size_t xrow2 = xrow + (size_t)64 * E_;
  const size_t wrow = (size_t)(col0 + srow) * E_ + sgcol;
  const size_t wrow2 = wrow + (size_t)64 * E_;

#define STAGE_(buf, k0_)                                          \
  do {                                                            \
    bf16_t* bp = smem + (buf) * 16384;                            \
    GLD_LDS16(X + xrow + (k0_), &bp[tid * 8]);                    \
    GLD_LDS16(X + xrow2 + (k0_), &bp[2048 + tid * 8]);            \
    GLD_LDS16(Wq + wrow + (k0_), &bp[4096 + tid * 8]);            \
    GLD_LDS16(Wq + wrow2 + (k0_), &bp[6144 + tid * 8]);           \
    GLD_LDS16(Wk + wrow + (k0_), &bp[8192 + tid * 8]);            \
    GLD_LDS16(Wk + wrow2 + (k0_), &bp[10240 + tid * 8]);          \
    GLD_LDS16(Wv + wrow + (k0_), &bp[12288 + tid * 8]);           \
    GLD_LDS16(Wv + wrow2 + (k0_), &bp[14336 + tid * 8]);          \
  } while (0)

#define COMPUTE_(buf)                                             \
  do {                                                            \
    const bf16_t* bp = smem + (buf) * 16384;                      \
    const int slot = (q4 ^ row0swz) << 3;                         \
    bf16x8 a[4];                                                  \
    _Pragma("unroll")                                             \
    for (int mi = 0; mi < 4; ++mi)                                \
      a[mi] = *(const bf16x8*)&bp[(rA + mi * 16 + l15) * 32 + slot]; \
    _Pragma("unroll")                                             \
    for (int m = 0; m < 3; ++m) {                                 \
      bf16x8 b[4];                                                \
      _Pragma("unroll")                                           \
      for (int ni = 0; ni < 4; ++ni)                              \
        b[ni] = *(const bf16x8*)&bp[4096 + m * 4096 +             \
                                    (cB + ni * 16 + l15) * 32 + slot]; \
      _Pragma("unroll")                                           \
      for (int mi = 0; mi < 4; ++mi)                              \
        _Pragma("unroll")                                         \
        for (int ni = 0; ni < 4; ++ni)                            \
          acc[m][mi][ni] = __builtin_amdgcn_mfma_f32_16x16x32_bf16( \
              a[mi], b[ni], acc[m][mi][ni], 0, 0, 0);             \
    }                                                             \
  } while (0)

  STAGE_(0, 0);
  __syncthreads();
  int cur = 0;
  for (int k0 = 32; k0 < E_; k0 += 32) {
    STAGE_(cur ^ 1, k0);   // issue next tile's loads first
    COMPUTE_(cur);         // ds_read + 48 MFMA on current tile
    __syncthreads();       // drain lands after the compute phase
    cur ^= 1;
  }
  COMPUTE_(cur);

#undef STAGE_
#undef COMPUTE_

  // ---- q/k rope epilogues (register-only; acc[0]=q, acc[1]=k) ----
  const int h = colTile * 2 + (w >> 1);  // head constant per wave
#pragma unroll
  for (int t = 0; t < 2; ++t) {
    const int slot = il * 2 + t;
    // q: SCALE (0.125) * log2(e) folded in (attn softmax runs in exp2 domain)
    const float post = (t == 0) ? 0.18033688011112042f : 1.0f;
#pragma unroll
    for (int mi = 0; mi < 4; ++mi) {
#pragma unroll
      for (int reg = 0; reg < 4; ++reg) {
        const int m = row0 + rA + mi * 16 + q4 * 4 + reg;
        const int b = m >> 10, l = m & (L_ - 1);
#pragma unroll
        for (int ni = 0; ni < 4; ++ni) {
          const int d = ni * 16 + l15;
          const float v0 = acc[t][mi][ni][reg];
          const float part = acc[t][mi][ni ^ 2][reg];  // value at d^32
          const float rot = (d < 32) ? -part : part;
          const float v = (v0 * cosb[l * D_ + d] + rot * sinb[l * D_ + d]) * post;
          qk[(((size_t)slot * B_ + b) * H_ + h) * ((size_t)L_ * D_) +
             (size_t)l * D_ + d] = (bf16_t)v;
        }
      }
    }
  }

  // ---- v: two-pass transpose via S[128][72] -> VT[il][b][h][d][l] ----
  {
    const int n_l = tid >> 1, lh = tid & 1;
    const int hv = colTile * 2 + (n_l >> 6), d = n_l & 63;
    const int bb = row0 >> 10;
    __syncthreads();  // all waves done reading staging bufs
#pragma unroll
    for (int p = 0; p < 2; ++p) {
      if ((w & 1) == p) {  // waves whose rA == p*64 own this m-half
#pragma unroll
        for (int mi = 0; mi < 4; ++mi)
#pragma unroll
          for (int reg = 0; reg < 4; ++reg)
#pragma unroll
            for (int ni = 0; ni < 4; ++ni)
              smem[(cB + ni * 16 + l15) * 72 + mi * 16 + q4 * 4 + reg] =
                  (bf16_t)acc[2][mi][ni][reg];
      }
      __syncthreads();
      // read-out: thread -> row n = tid>>1 (h,d), half lh = tid&1 (32 l)
      const int l0 = (row0 & (L_ - 1)) + p * 64 + lh * 32;
      bf16_t* gp = vt + (((size_t)il * B_ + bb) * H_ + hv) * ((size_t)D_ * L_) +
                   (size_t)d * L_ + l0;
      const bf16_t* sp = &smem[n_l * 72 + lh * 32];
#pragma unroll
      for (int c = 0; c < 4; ++c)
        *(bf16x8*)(gp + c * 8) = *(const bf16x8*)(sp + c * 8);
      if (p == 0) __syncthreads();  // before overwriting S with half 1
    }
  }
}

// ---------------------------------------------------------------------------
// Wo projection: out = xn (2048 x 1024) * Wo^T, fp32 output. r13 structure:
// 128x128 tile, BK=32 dbuf, same swizzle, XCD-chunked (grid (16,8)).
// ---------------------------------------------------------------------------
__global__ __launch_bounds__(256) void wo_k(
    const bf16_t* __restrict__ X, const bf16_t* __restrict__ W,
    float* __restrict__ outf)
{
  __shared__ bf16_t smem[16384];  // 32 KB: 2 bufs x (X 8K + W 8K bytes)
  const int tid = threadIdx.x;
  const int lane = tid & 63;
  const int w = tid >> 6;
  const int q4 = lane >> 4, l15 = lane & 15;
  const int row0swz = (l15 >> 1) & 3;

  const int flat0 = blockIdx.y * 16 + blockIdx.x;
  const int nf = (flat0 & 7) * 16 + (flat0 >> 3);
  const int bxs = nf & 15;
  const int bys = nf >> 4;
  const int row0 = bxs * 128;
  const int col0 = bys * 128;
  const int rA = (w & 1) * 64;
  const int cB = (w >> 1) * 64;

  const int srow = tid >> 2;
  const int sgcol = (((tid & 3) ^ ((tid >> 3) & 3)) << 3);

  f32x4 acc[4][4] = {};

  const size_t xrow = (size_t)(row0 + srow) * E_ + sgcol;
  const size_t xrow2 = xrow + (size_t)64 * E_;
  const size_t wrow = (size_t)(col0 + srow) * E_ + sgcol;
  const size_t wrow2 = wrow + (size_t)64 * E_;

#define STAGE_(buf, k0_)                                         \
  do {                                                           \
    bf16_t* Xb = smem + (buf) * 8192;                            \
    bf16_t* Wbl = smem + (buf) * 8192 + 4096;                    \
    GLD_LDS16(X + xrow + (k0_), &Xb[tid * 8]);                   \
    GLD_LDS16(X + xrow2 + (k0_), &Xb[2048 + tid * 8]);           \
    GLD_LDS16(W + wrow + (k0_), &Wbl[tid * 8]);                  \
    GLD_LDS16(W + wrow2 + (k0_), &Wbl[2048 + tid * 8]);          \
  } while (0)

#define COMPUTE_(buf)                                            \
  do {                                                           \
    const bf16_t* Xb = smem + (buf) * 8192;                      \
    const bf16_t* Wbl = smem + (buf) * 8192 + 4096;              \
    bf16x8 a[4], b[4];                                           \
    const int slot = (q4 ^ row0swz) << 3;                        \
    _Pragma("unroll")                                            \
    for (int mi = 0; mi < 4; ++mi)                               \
      a[mi] = *(const bf16x8*)&Xb[(rA + mi * 16 + l15) * 32 + slot]; \
    _Pragma("unroll")                                            \
    for (int ni = 0; ni < 4; ++ni)                               \
      b[ni] = *(const bf16x8*)&Wbl[(cB + ni * 16 + l15) * 32 + slot]; \
    _Pragma("unroll")                                            \
    for (int mi = 0; mi < 4; ++mi)                               \
      _Pragma("unroll")                                          \
      for (int ni = 0; ni < 4; ++ni)                             \
        acc[mi][ni] = __builtin_amdgcn_mfma_f32_16x16x32_bf16(   \
            a[mi], b[ni], acc[mi][ni], 0, 0, 0);                 \
  } while (0)

  STAGE_(0, 0);
  __syncthreads();
  int cur = 0;
  for (int k0 = 32; k0 < E_; k0 += 32) {
    STAGE_(cur ^ 1, k0);
    COMPUTE_(cur);
    __syncthreads();
    cur ^= 1;
  }
  COMPUTE_(cur);

#undef STAGE_
#undef COMPUTE_

#pragma unroll
  for (int mi = 0; mi < 4; ++mi) {
#pragma unroll
    for (int reg = 0; reg < 4; ++reg) {
      const int m = row0 + rA + mi * 16 + q4 * 4 + reg;
#pragma unroll
      for (int ni = 0; ni < 4; ++ni) {
        const int n = col0 + cB + ni * 16 + l15;
        outf[(size_t)m * E_ + n] = acc[mi][ni][reg];
      }
    }
  }
}

// ---------------------------------------------------------------------------
// Flash attention, BQ=64 / BK=64, complementary-qt pairing: block x handles
// q-tile (15-x) then q-tile x -> uniform 17 KV tiles per block, 768 blocks =
// exactly 3/CU, zero tail. NO-MAX softmax: scores (exp2 domain, q pre-scaled
// by SCALE*log2e) are bounded, so P = exp2(s) directly; O and l are plain
// sums (no rescale, no shfl). Row sums l via MFMA against all-ones fragment.
// K/V double-buffered with XOR-swizzled LDS. XCD-chunked block swizzle:
// the 8 q-tile blocks sharing one (i,b,h)'s 512 KB K/V land on one XCD.
// ---------------------------------------------------------------------------
__global__ __launch_bounds__(256) void attn_k(const bf16_t* __restrict__ qk,
                                              const bf16_t* __restrict__ vt,
                                              bf16_t* __restrict__ attn)
{
  __shared__ bf16_t Ks[2][64 * 64];
  __shared__ bf16_t Vts[2][64 * 64];   // [d][l] within tile (swizzled cols)
  __shared__ bf16_t Ps[4][16 * 72];    // per-wave 16x64 P tile, padded rows

  const int tid = threadIdx.x, lane = tid & 63, w = tid >> 6;
  const int q4 = lane >> 4, l15 = lane & 15;

  // XCD-chunked swizzle: grid (8, 96), n=768, chunk=96
  const int flat0 = blockIdx.y * 8 + blockIdx.x;
  const int nf = (flat0 & 7) * 96 + (flat0 >> 3);
  const int x = nf & 7;   // 0..7 (paired q-tile index)
  const int by = nf >> 3;

  const int h = by & 15, b = (by >> 4) & 1, i = by >> 5;
  const size_t HD = (size_t)L_ * D_;
  const bf16_t* Qp = qk + (((size_t)(i * 2 + 0) * B_ + b) * H_ + h) * HD;
  const bf16_t* Kp = qk + (((size_t)(i * 2 + 1) * B_ + b) * H_ + h) * HD;
  const bf16_t* Vp = vt + (((size_t)i * B_ + b) * H_ + h) * HD;  // [d][l]

  // per-thread staging geometry (swizzled global column group)
  const int srow = tid >> 3;               // row within half-tile (it adds 32)
  const int sg = tid & 7;                  // LDS col group 0..7 (8 elems each)
  const int scol = (sg ^ (srow & 7)) * 8;  // global col for this LDS slot

  // all-ones B fragment for row sums
  bf16x8 ones;
#pragma unroll
  for (int jj = 0; jj < 8; ++jj) ones[jj] = (bf16_t)1.0f;

#pragma unroll 1
  for (int ph = 0; ph < 2; ++ph) {
    const int qt = ph == 0 ? (15 - x) : x;  // paired: work = 17 tiles total

    // Q fragments in registers (A-layout: row = l15, k = q4*8 within kk-half)
    bf16x8 aq[2];
#pragma unroll
    for (int kk = 0; kk < 2; ++kk)
      aq[kk] = *(const bf16x8*)(Qp + (size_t)(qt * 64 + w * 16 + l15) * 64 +
                                kk * 32 + q4 * 8);

    if (ph == 1) __syncthreads();  // all waves done reading phase-0 buffers
#pragma unroll
    for (int it = 0; it < 2; ++it) {  // stage KV tile 0 (swizzled)
      const int flat = it * 2048 + tid * 8;
      const int r = it * 32 + srow;
      GLD_LDS16(Kp + r * 64 + scol, &Ks[0][flat]);
      GLD_LDS16(Vp + (size_t)r * L_ + scol, &Vts[0][flat]);
    }

    f32x4 o[4] = {};
    f32x4 lacc = {};

#pragma unroll 1
    for (int j = 0; j <= qt; ++j) {
      __syncthreads();  // tile j landed (vmcnt drain at barrier)
      const int cur = j & 1;
      if (j < qt) {  // prefetch j+1; lands during compute of j
        const int nxt = cur ^ 1;
#pragma unroll
        for (int it = 0; it < 2; ++it) {
          const int flat = it * 2048 + tid * 8;
          const int r = it * 32 + srow;
          GLD_LDS16(Kp + (j + 1) * 4096 + r * 64 + scol, &Ks[nxt][flat]);
          GLD_LDS16(Vp + (size_t)r * L_ + (j + 1) * 64 + scol, &Vts[nxt][flat]);
        }
      }

      // S = Q K^T (swizzled K read: colgrp = (kk*4+q4) ^ (l15&7))
      f32x4 s[4] = {};
#pragma unroll
      for (int kk = 0; kk < 2; ++kk) {
#pragma unroll
        for (int ni = 0; ni < 4; ++ni) {
          const bf16x8 bk =
              *(const bf16x8*)&Ks[cur][(ni * 16 + l15) * 64 +
                                       (((kk * 4 + q4) ^ (l15 & 7)) << 3)];
          s[ni] = __builtin_amdgcn_mfma_f32_16x16x32_bf16(aq[kk], bk, s[ni], 0, 0, 0);
        }
      }

      if (j == qt) {  // diagonal tile: mask cols > row within tile
#pragma unroll
        for (int reg = 0; reg < 4; ++reg)
#pragma unroll
          for (int ni = 0; ni < 4; ++ni)
            if (ni * 16 + l15 > w * 16 + q4 * 4 + reg) s[ni][reg] = NEG_INF;
      }

      // P = exp2(s) (no max subtraction; bounded scores), store to Ps
#pragma unroll
      for (int reg = 0; reg < 4; ++reg)
#pragma unroll
        for (int ni = 0; ni < 4; ++ni)
          Ps[w][(q4 * 4 + reg) * 72 + ni * 16 + l15] = (bf16_t)exp2f(s[ni][reg]);
      // Ps is wave-private: LDS write->read completion only
      asm volatile("s_waitcnt lgkmcnt(0)" ::: "memory");

      // O += P V ; l += P . 1  (V^T in LDS, swizzled like K)
#pragma unroll
      for (int kk = 0; kk < 2; ++kk) {
        const bf16x8 ap = *(const bf16x8*)&Ps[w][l15 * 72 + kk * 32 + q4 * 8];
        lacc = __builtin_amdgcn_mfma_f32_16x16x32_bf16(ap, ones, lacc, 0, 0, 0);
#pragma unroll
        for (int di = 0; di < 4; ++di) {
          const bf16x8 bv =
              *(const bf16x8*)&Vts[cur][(di * 16 + l15) * 64 +
                                        (((kk * 4 + q4) ^ (l15 & 7)) << 3)];
          o[di] = __builtin_amdgcn_mfma_f32_16x16x32_bf16(ap, bv, o[di], 0, 0, 0);
        }
      }
    }

    const int row_base = (i * B_ + b) * L_ + qt * 64 + w * 16 + q4 * 4;
#pragma unroll
    for (int reg = 0; reg < 4; ++reg) {
      const float inv = 1.f / lacc[reg];
      const int r = row_base + reg;
#pragma unroll
      for (int di = 0; di < 4; ++di)
        attn[(size_t)r * E_ + h * 64 + di * 16 + l15] = (bf16_t)(o[di][reg] * inv);
    }
  }
}

// ---------------------------------------------------------------------------
// Combine: per (b,l) row: sum_i rmsnorm(a_i)*g_ln[i]*lw[i] + alpha*x, then
// final rmsnorm with g_final -> bf16 row (input to Wo GEMM).
// ---------------------------------------------------------------------------
__device__ __forceinline__ float block_sum(float v, float* sm)
{
#pragma unroll
  for (int off = 32; off > 0; off >>= 1) v += __shfl_xor(v, off);
  const int w = threadIdx.x >> 6;
  __syncthreads();
  if ((threadIdx.x & 63) == 0) sm[w] = v;
  __syncthreads();
  return sm[0] + sm[1] + sm[2] + sm[3];
}

__global__ __launch_bounds__(256) void combine_k(
    const bf16_t* __restrict__ attn, const float* __restrict__ x,
    const float* __restrict__ g_ln, const float* __restrict__ lambdas,
    const float* __restrict__ g_final, const float* __restrict__ alphap,
    bf16_t* __restrict__ xn)
{
  __shared__ float sm[4];
  const int row = blockIdx.x;
  const int tid = threadIdx.x;

  // lambda weights: sigmoid -> non-affine LayerNorm over NL=3
  float sg[3], lw[3];
#pragma unroll
  for (int i = 0; i < 3; ++i) sg[i] = 1.f / (1.f + expf(-lambdas[i]));
  const float mean = (sg[0] + sg[1] + sg[2]) * (1.f / 3.f);
  const float var = ((sg[0] - mean) * (sg[0] - mean) + (sg[1] - mean) * (sg[1] - mean) +
                     (sg[2] - mean) * (sg[2] - mean)) * (1.f / 3.f);
  const float rv = rsqrtf(var + 1e-5f);
#pragma unroll
  for (int i = 0; i < 3; ++i) lw[i] = (sg[i] - mean) * rv;

  const float av = alphap[0];
  float c[4];
#pragma unroll
  for (int k = 0; k < 4; ++k) {
    const int e = tid + k * 256;
    c[k] = av * x[(size_t)row * E_ + e];
  }

  for (int i = 0; i < 3; ++i) {
    float a[4];
    float ss = 0.f;
#pragma unroll
    for (int k = 0; k < 4; ++k) {
      const int e = tid + k * 256;
      a[k] = (float)attn[((size_t)i * (B_ * L_) + row) * E_ + e];
      ss += a[k] * a[k];
    }
    ss = block_sum(ss, sm);
    const float rinv = rsqrtf(ss * (1.f / (float)E_) + 1e-5f);
#pragma unroll
    for (int k = 0; k < 4; ++k) {
      const int e = tid + k * 256;
      c[k] += a[k] * rinv * g_ln[i * E_ + e] * lw[i];
    }
  }

  float ss = 0.f;
#pragma unroll
  for (int k = 0; k < 4; ++k) ss += c[k] * c[k];
  ss = block_sum(ss, sm);
  const float rinv = rsqrtf(ss * (1.f / (float)E_) + 1e-5f);
#pragma unroll
  for (int k = 0; k < 4; ++k) {
    const int e = tid + k * 256;
    xn[(size_t)row * E_ + e] = (bf16_t)(c[k] * rinv * g_final[e]);
  }
}

// ---------------------------------------------------------------------------
extern "C" void kernel_launch(void* const* d_in, const int* in_sizes, int n_in,
                              void* d_out, int out_size, void* d_ws, size_t ws_size,
                              hipStream_t stream)
{
  const float* x       = (const float*)d_in[0];
  const float* cosb    = (const float*)d_in[1];
  const float* sinb    = (const float*)d_in[2];
  // d_in[3] attn_mask: unused (causal mask applied analytically)
  const float* Wq      = (const float*)d_in[4];
  const float* Wk      = (const float*)d_in[5];
  const float* Wv      = (const float*)d_in[6];
  const float* g_ln    = (const float*)d_in[7];
  const float* lambdas = (const float*)d_in[8];
  const float* Wo      = (const float*)d_in[9];
  const float* g_final = (const float*)d_in[10];
  const float* alphap  = (const float*)d_in[11];

  // ws layout (bytes) — 75,497,472 total:
  //   qk    bf16 [6][B][H][L][D]  @ 0           25,165,824
  //   VT    bf16 [3][B][H][D][L]  @ 25,165,824  12,582,912
  //   attnb bf16 [3][B*L][E]      @ 37,748,736  12,582,912
  //   Wqkvb bf16 [3][NL][E][E]    @ 50,331,648  18,874,368
  //   Wob   bf16 [E][E]           @ 69,206,016   2,097,152
  //   xb    bf16 [B*L][E]         @ 71,303,168   4,194,304
  //   xnb   bf16 [B*L][E]         @ 0 (aliases dead qk)
  bf16_t* qk    = (bf16_t*)d_ws;
  bf16_t* VT    = (bf16_t*)((char*)d_ws + 25165824);
  bf16_t* attnb = (bf16_t*)((char*)d_ws + 37748736);
  bf16_t* Wqb   = (bf16_t*)((char*)d_ws + 50331648);
  bf16_t* Wkb   = Wqb + 3145728;
  bf16_t* Wvb   = Wkb + 3145728;
  bf16_t* Wob   = (bf16_t*)((char*)d_ws + 69206016);
  bf16_t* xb    = (bf16_t*)((char*)d_ws + 71303168);
  bf16_t* xnb   = (bf16_t*)d_ws;  // alias: qk dead after attn_k
  float*  out   = (float*)d_out;   // reference output dtype is float32

  // 0) fp32 -> bf16 conversion of weights + x
  cvt_k<<<dim3(3072, 5), 256, 0, stream>>>(Wq, Wk, Wv, Wo, x, Wqb, Wkb, Wvb, Wob, xb);
  // 1) fused QKV projections + rope / V-transpose: grid (16 rows, 8 cols x 3 layers)
  gemmqkv_k<<<dim3(16, 24), 256, 0, stream>>>(xb, Wqb, Wkb, Wvb, cosb, sinb,
                                              qk, VT);
  // 2) flash attention: grid (8 paired q-tiles, NL*B*H = 96)
  attn_k<<<dim3(8, 96), 256, 0, stream>>>(qk, VT, attnb);
  // 3) combine + final rmsnorm: one block per (b,l) row
  combine_k<<<dim3(B_ * L_), 256, 0, stream>>>(attnb, x, g_ln, lambdas, g_final,
                                               alphap, xnb);
  // 4) output projection @ Wo^T -> fp32 d_out
  wo_k<<<dim3(16, 8), 256, 0, stream>>>(xnb, Wob, out);
}

// Round 10
// 229.072 us; speedup vs baseline: 1.0857x; 1.0857x over previous
//
#include <hip/hip_runtime.h>

// IntrospectiveAttention on MI355X (gfx950).
// The growing KV cache is dead code (mask = -inf past L); each layer is plain
// causal attention over its own fresh q/k/v. Pipeline:
//   0) cvt_k:     fp32 -> bf16 pre-convert of x/Wq/Wk/Wv/Wo
//   1) gemm_k<0>: QKV projections. BK=32, TWO-buffer counted-vmcnt pipeline:
//                 leading "s_waitcnt vmcnt(4); s_barrier" (tile t ready, tile
//                 t+1 stays in flight -- never vmcnt(0) mid-loop) + trailing
//                 plain s_barrier (WAR: reads of buf t&1 finish before iter
//                 t+1 restages it; needed since 2 buffers < lookahead+2).
//                 (r15-r17 FAILED: 4 buffers x 8192 elems indexed into a
//                 16384-elem smem array -> OOB at +32..64KB, deterministic
//                 absmax 4.64. Identical absmax across barrier variants was
//                 the tell: arithmetic bug, not a race.)
//                 32 KB LDS -> 5 blocks/CU preserved. XCD-chunked swizzle.
//                 q: rope*(SCALE*log2e); k: rope; v: two-pass LDS transpose.
//   2) attn_k:    flash attention, BQ=64, complementary-qt pairing, no-max
//                 exp2 softmax, row sums via ones-MFMA, swizzled K/V dbuf,
//                 XCD-chunked swizzle (8 blocks share one 512 KB KV head)
//   3) combine_k: rmsnorm*lw sum + alpha*x + final rmsnorm -> bf16 xn
//   4) gemm_k<1>: xn @ Wo^T -> fp32 d_out (same counted-vmcnt loop)

#define B_  2
#define L_  1024
#define E_  1024
#define H_  16
#define NL_ 3
#define D_  64

typedef __bf16 bf16_t;
typedef __bf16 bf16x8 __attribute__((ext_vector_type(8)));
typedef __bf16 bf16x4 __attribute__((ext_vector_type(4)));
typedef float  f32x4  __attribute__((ext_vector_type(4)));

#define NEG_INF (-__builtin_inff())

typedef const __attribute__((address_space(1))) void* gas_ptr;
typedef __attribute__((address_space(3))) void* las_ptr;

// async global->LDS, 16B per lane; HW dest = wave-uniform base + lane*16
#define GLD_LDS16(gp, lp) \
  __builtin_amdgcn_global_load_lds((gas_ptr)(gp), (las_ptr)(lp), 16, 0, 0)

// ---------------------------------------------------------------------------
// fp32 -> bf16 convert: segs = Wq/Wk/Wv (3,145,728 ea), Wo (1,048,576),
// x (2,097,152). grid (3072, 5) x 256, 4 elems/thread.
// ---------------------------------------------------------------------------
__global__ __launch_bounds__(256) void cvt_k(
    const float* __restrict__ s0, const float* __restrict__ s1,
    const float* __restrict__ s2, const float* __restrict__ s3,
    const float* __restrict__ s4, bf16_t* __restrict__ d0,
    bf16_t* __restrict__ d1, bf16_t* __restrict__ d2, bf16_t* __restrict__ d3,
    bf16_t* __restrict__ d4)
{
  const int seg = blockIdx.y;
  const float* s;
  bf16_t* d;
  int n;
  if (seg == 0)      { s = s0; d = d0; n = 3145728; }
  else if (seg == 1) { s = s1; d = d1; n = 3145728; }
  else if (seg == 2) { s = s2; d = d2; n = 3145728; }
  else if (seg == 3) { s = s3; d = d3; n = 1048576; }
  else               { s = s4; d = d4; n = 2097152; }
  const int i = (blockIdx.x * 256 + threadIdx.x) * 4;
  if (i < n) {
    const float4 v = *(const float4*)(s + i);
    bf16x4 o;
    o[0] = (bf16_t)v.x; o[1] = (bf16_t)v.y; o[2] = (bf16_t)v.z; o[3] = (bf16_t)v.w;
    *(bf16x4*)(d + i) = o;
  }
}

// ---------------------------------------------------------------------------
// GEMM: C = X (M x K) * W^T, X/W bf16 row-major (W is N x K). 128x128 tile,
// BK=32, 2-buffer global_load_lds staging with XOR swizzle on 16 B groups:
//   LDS[row][g] = Global[row][g ^ ((row>>1)&3)]
// Counted-vmcnt pipeline (lookahead 1):
//   iter t: STAGE((t+1)&1, t+1)
//           "s_waitcnt vmcnt(4); s_barrier"   // tile t landed; t+1 in flight
//           COMPUTE(t&1)
//           "s_barrier"                        // WAR: buf t&1 safe to restage
// - vmcnt(4) retires tile t's 4 loads (oldest; vmcnt retires in issue
//   order); the leading barrier makes that cross-wave. Tile t+1's loads
//   cross BOTH barriers and are retired by the next iter's vmcnt(4).
// - The trailing barrier carries no waitcnt (ds_reads are consumed by the
//   MFMAs above it); it only orders reads before the next stage-overwrite.
// - Both barriers are asm volatile with "memory" clobber: ds_reads cannot
//   hoist, stage loads cannot sink (raw __builtin s_barrier is IntrNoMem).
// - Buffer layout (fits smem[16384] exactly): buf b at b*8192; X rows
//   0..63 @ +0, 64..127 @ +2048; W @ +4096 / +6144.
// Block ids are XCD-chunk swizzled (each XCD gets a contiguous work range).
// EPI==0: 9 QKV mats. t==0 (q): rope * SCALE*log2e; t==1 (k): rope;
//         t==2 (v): two-pass transpose -> VT[il][b][h][d][l].
// EPI==1: fp32 accumulator store to outf (Wo projection -> d_out).
// ---------------------------------------------------------------------------
template <int EPI>
__global__ __launch_bounds__(256) void gemm_k(
    const bf16_t* __restrict__ X, const bf16_t* __restrict__ W0,
    const bf16_t* __restrict__ W1, const bf16_t* __restrict__ W2,
    const float* __restrict__ cosb, const float* __restrict__ sinb,
    bf16_t* __restrict__ qk, bf16_t* __restrict__ vt, float* __restrict__ outf)
{
  // 2 staging buffers of (X:128x32 + W:128x32) bf16 = 16 KB each, 32 KB
  // total. V-transpose view: S[128][72] (18.4 KB), reused after K-loop.
  __shared__ bf16_t smem[16384];
  const int tid = threadIdx.x;
  const int lane = tid & 63;
  const int w = tid >> 6;
  const int q4 = lane >> 4, l15 = lane & 15;
  const int row0swz = (l15 >> 1) & 3;  // (row>>1)&3 for rows rX + mi*16 + l15

  // XCD-chunked block swizzle (grid is 16 x 72 for EPI=0, 16 x 8 for EPI=1;
  // both n%8==0 -> bijective)
  const int flat0 = blockIdx.y * 16 + blockIdx.x;
  const int chunk = (EPI ? 128 : 1152) >> 3;
  const int nf = (flat0 & 7) * chunk + (flat0 >> 3);
  const int bxs = nf & 15;
  const int bys = nf >> 4;

  const int row0 = bxs * 128;

  int g, tileN;
  const bf16_t* Wb;
  if (EPI == 0) {
    g = bys >> 3;
    tileN = bys & 7;
    const int t = g % 3, il = g / 3;
    Wb = (t == 0 ? W0 : (t == 1 ? W1 : W2)) + (size_t)il * E_ * E_;
  } else {
    g = 0;
    tileN = bys;
    Wb = W0;
  }
  const int col0 = tileN * 128;
  const int rA = (w & 1) * 64;   // wave's row sub-tile
  const int cB = (w >> 1) * 64;  // wave's col sub-tile

  // staging geometry: thread -> (row = slab*64 + tid>>2, 16 B group tid&3),
  // swizzled global group = (tid&3) ^ ((row>>1)&3) = (tid&3) ^ ((tid>>3)&3)
  const int srow = tid >> 2;                       // row within 64-row slab
  const int sgcol = (((tid & 3) ^ ((tid >> 3) & 3)) << 3);  // global col

  f32x4 acc[4][4] = {};

  const size_t xrow = (size_t)(row0 + srow) * E_ + sgcol;
  const size_t xrow2 = xrow + (size_t)64 * E_;
  const size_t wrow = (size_t)(col0 + srow) * E_ + sgcol;
  const size_t wrow2 = wrow + (size_t)64 * E_;

#define STAGE_(buf, st)                                          \
  do {                                                           \
    bf16_t* Xb = smem + (buf) * 8192;                            \
    bf16_t* Wbl = smem + (buf) * 8192 + 4096;                    \
    const int k0_ = (st) * 32;                                   \
    GLD_LDS16(X + xrow + k0_, &Xb[tid * 8]);                     \
    GLD_LDS16(X + xrow2 + k0_, &Xb[2048 + tid * 8]);             \
    GLD_LDS16(Wb + wrow + k0_, &Wbl[tid * 8]);                   \
    GLD_LDS16(Wb + wrow2 + k0_, &Wbl[2048 + tid * 8]);           \
  } while (0)

#define COMPUTE_(buf)                                            \
  do {                                                           \
    const bf16_t* Xb = smem + (buf) * 8192;                      \
    const bf16_t* Wbl = smem + (buf) * 8192 + 4096;              \
    bf16x8 a[4], b[4];                                           \
    const int slot = (q4 ^ row0swz) << 3;                        \
    _Pragma("unroll")                                            \
    for (int mi = 0; mi < 4; ++mi)                               \
      a[mi] = *(const bf16x8*)&Xb[(rA + mi * 16 + l15) * 32 + slot]; \
    _Pragma("unroll")                                            \
    for (int ni = 0; ni < 4; ++ni)                               \
      b[ni] = *(const bf16x8*)&Wbl[(cB + ni * 16 + l15) * 32 + slot]; \
    _Pragma("unroll")                                            \
    for (int mi = 0; mi < 4; ++mi)                               \
      _Pragma("unroll")                                          \
      for (int ni = 0; ni < 4; ++ni)                             \
        acc[mi][ni] = __builtin_amdgcn_mfma_f32_16x16x32_bf16(   \
            a[mi], b[ni], acc[mi][ni], 0, 0, 0);                 \
  } while (0)

  // prologue: tile 0 in flight
  STAGE_(0, 0);
#pragma unroll 1
  for (int t = 0; t < 31; ++t) {
    STAGE_((t + 1) & 1, t + 1);  // issue next tile (4 loads)
    // tile t ready (retire oldest 4; tile t+1 stays in flight), cross-wave
    asm volatile("s_waitcnt vmcnt(4)\n\ts_barrier" ::: "memory");
    COMPUTE_(t & 1);
    // reads of buf t&1 done before iter t+1 restages it
    asm volatile("s_barrier" ::: "memory");
  }
  asm volatile("s_waitcnt vmcnt(0)\n\ts_barrier" ::: "memory");
  COMPUTE_(1);  // t = 31

#undef STAGE_
#undef COMPUTE_

  if (EPI == 0) {
    const int t = g % 3, il = g / 3;
    if (t < 2) {  // q,k: rope epilogue, [slot][b][h][l][d]
      const int slot = il * 2 + t;
      const int h = tileN * 2 + (w >> 1);  // head constant per wave
      // q: SCALE (0.125) * log2(e) folded in (attn softmax runs in exp2 domain)
      const float post = (t == 0) ? 0.18033688011112042f : 1.0f;
#pragma unroll
      for (int mi = 0; mi < 4; ++mi) {
#pragma unroll
        for (int reg = 0; reg < 4; ++reg) {
          const int m = row0 + rA + mi * 16 + q4 * 4 + reg;
          const int b = m >> 10, l = m & (L_ - 1);
#pragma unroll
          for (int ni = 0; ni < 4; ++ni) {
            const int d = ni * 16 + l15;
            const float v0 = acc[mi][ni][reg];
            const float part = acc[mi][ni ^ 2][reg];  // value at d^32, same lane
            const float rot = (d < 32) ? -part : part;
            const float v = (v0 * cosb[l * D_ + d] + rot * sinb[l * D_ + d]) * post;
            qk[(((size_t)slot * B_ + b) * H_ + h) * ((size_t)L_ * D_) +
               (size_t)l * D_ + d] = (bf16_t)v;
          }
        }
      }
    } else {  // v: two-pass transpose via S[128][72] -> VT[il][b][h][d][l]
      const int n_l = tid >> 1, lh = tid & 1;
      const int h = tileN * 2 + (n_l >> 6), d = n_l & 63;
      const int bb = row0 >> 10;
      __syncthreads();  // all waves done reading staging bufs
#pragma unroll
      for (int p = 0; p < 2; ++p) {
        if ((w & 1) == p) {  // waves whose rA == p*64 own this m-half
#pragma unroll
          for (int mi = 0; mi < 4; ++mi)
#pragma unroll
            for (int reg = 0; reg < 4; ++reg)
#pragma unroll
              for (int ni = 0; ni < 4; ++ni)
                smem[(cB + ni * 16 + l15) * 72 + mi * 16 + q4 * 4 + reg] =
                    (bf16_t)acc[mi][ni][reg];
        }
        __syncthreads();
        // read-out: thread -> row n = tid>>1 (h,d), half lh = tid&1 (32 l)
        const int l0 = (row0 & (L_ - 1)) + p * 64 + lh * 32;
        bf16_t* gp = vt + (((size_t)il * B_ + bb) * H_ + h) * ((size_t)D_ * L_) +
                     (size_t)d * L_ + l0;
        const bf16_t* sp = &smem[n_l * 72 + lh * 32];
#pragma unroll
        for (int c = 0; c < 4; ++c)
          *(bf16x8*)(gp + c * 8) = *(const bf16x8*)(sp + c * 8);
        if (p == 0) __syncthreads();  // before overwriting S with half 1
      }
    }
  } else {
#pragma unroll
    for (int mi = 0; mi < 4; ++mi) {
#pragma unroll
      for (int reg = 0; reg < 4; ++reg) {
        const int m = row0 + rA + mi * 16 + q4 * 4 + reg;
#pragma unroll
        for (int ni = 0; ni < 4; ++ni) {
          const int n = col0 + cB + ni * 16 + l15;
          outf[(size_t)m * E_ + n] = acc[mi][ni][reg];  // fp32 output
        }
      }
    }
  }
}

// ---------------------------------------------------------------------------
// Flash attention, BQ=64 / BK=64, complementary-qt pairing: block x handles
// q-tile (15-x) then q-tile x -> uniform 17 KV tiles per block, 768 blocks =
// exactly 3/CU, zero tail. NO-MAX softmax: scores (exp2 domain, q pre-scaled
// by SCALE*log2e) are bounded, so P = exp2(s) directly; O and l are plain
// sums (no rescale, no shfl). Row sums l via MFMA against all-ones fragment.
// K/V double-buffered with XOR-swizzled LDS. XCD-chunked block swizzle:
// the 8 q-tile blocks sharing one (i,b,h)'s 512 KB K/V land on one XCD.
// ---------------------------------------------------------------------------
__global__ __launch_bounds__(256) void attn_k(const bf16_t* __restrict__ qk,
                                              const bf16_t* __restrict__ vt,
                                              bf16_t* __restrict__ attn)
{
  __shared__ bf16_t Ks[2][64 * 64];
  __shared__ bf16_t Vts[2][64 * 64];   // [d][l] within tile (swizzled cols)
  __shared__ bf16_t Ps[4][16 * 72];    // per-wave 16x64 P tile, padded rows

  const int tid = threadIdx.x, lane = tid & 63, w = tid >> 6;
  const int q4 = lane >> 4, l15 = lane & 15;

  // XCD-chunked swizzle: grid (8, 96), n=768, chunk=96
  const int flat0 = blockIdx.y * 8 + blockIdx.x;
  const int nf = (flat0 & 7) * 96 + (flat0 >> 3);
  const int x = nf & 7;   // 0..7 (paired q-tile index)
  const int by = nf >> 3;

  const int h = by & 15, b = (by >> 4) & 1, i = by >> 5;
  const size_t HD = (size_t)L_ * D_;
  const bf16_t* Qp = qk + (((size_t)(i * 2 + 0) * B_ + b) * H_ + h) * HD;
  const bf16_t* Kp = qk + (((size_t)(i * 2 + 1) * B_ + b) * H_ + h) * HD;
  const bf16_t* Vp = vt + (((size_t)i * B_ + b) * H_ + h) * HD;  // [d][l]

  // per-thread staging geometry (swizzled global column group)
  const int srow = tid >> 3;               // row within half-tile (it adds 32)
  const int sg = tid & 7;                  // LDS col group 0..7 (8 elems each)
  const int scol = (sg ^ (srow & 7)) * 8;  // global col for this LDS slot

  // all-ones B fragment for row sums
  bf16x8 ones;
#pragma unroll
  for (int jj = 0; jj < 8; ++jj) ones[jj] = (bf16_t)1.0f;

#pragma unroll 1
  for (int ph = 0; ph < 2; ++ph) {
    const int qt = ph == 0 ? (15 - x) : x;  // paired: work = 17 tiles total

    // Q fragments in registers (A-layout: row = l15, k = q4*8 within kk-half)
    bf16x8 aq[2];
#pragma unroll
    for (int kk = 0; kk < 2; ++kk)
      aq[kk] = *(const bf16x8*)(Qp + (size_t)(qt * 64 + w * 16 + l15) * 64 +
                                kk * 32 + q4 * 8);

    if (ph == 1) __syncthreads();  // all waves done reading phase-0 buffers
#pragma unroll
    for (int it = 0; it < 2; ++it) {  // stage KV tile 0 (swizzled)
      const int flat = it * 2048 + tid * 8;
      const int r = it * 32 + srow;
      GLD_LDS16(Kp + r * 64 + scol, &Ks[0][flat]);
      GLD_LDS16(Vp + (size_t)r * L_ + scol, &Vts[0][flat]);
    }

    f32x4 o[4] = {};
    f32x4 lacc = {};

#pragma unroll 1
    for (int j = 0; j <= qt; ++j) {
      __syncthreads();  // tile j landed (vmcnt drain at barrier)
      const int cur = j & 1;
      if (j < qt) {  // prefetch j+1; lands during compute of j
        const int nxt = cur ^ 1;
#pragma unroll
        for (int it = 0; it < 2; ++it) {
          const int flat = it * 2048 + tid * 8;
          const int r = it * 32 + srow;
          GLD_LDS16(Kp + (j + 1) * 4096 + r * 64 + scol, &Ks[nxt][flat]);
          GLD_LDS16(Vp + (size_t)r * L_ + (j + 1) * 64 + scol, &Vts[nxt][flat]);
        }
      }

      // S = Q K^T (swizzled K read: colgrp = (kk*4+q4) ^ (l15&7))
      f32x4 s[4] = {};
#pragma unroll
      for (int kk = 0; kk < 2; ++kk) {
#pragma unroll
        for (int ni = 0; ni < 4; ++ni) {
          const bf16x8 bk =
              *(const bf16x8*)&Ks[cur][(ni * 16 + l15) * 64 +
                                       (((kk * 4 + q4) ^ (l15 & 7)) << 3)];
          s[ni] = __builtin_amdgcn_mfma_f32_16x16x32_bf16(aq[kk], bk, s[ni], 0, 0, 0);
        }
      }

      if (j == qt) {  // diagonal tile: mask cols > row within tile
#pragma unroll
        for (int reg = 0; reg < 4; ++reg)
#pragma unroll
          for (int ni = 0; ni < 4; ++ni)
            if (ni * 16 + l15 > w * 16 + q4 * 4 + reg) s[ni][reg] = NEG_INF;
      }

      // P = exp2(s) (no max subtraction; bounded scores), store to Ps
#pragma unroll
      for (int reg = 0; reg < 4; ++reg)
#pragma unroll
        for (int ni = 0; ni < 4; ++ni)
          Ps[w][(q4 * 4 + reg) * 72 + ni * 16 + l15] = (bf16_t)exp2f(s[ni][reg]);
      // Ps is wave-private: LDS write->read completion only
      asm volatile("s_waitcnt lgkmcnt(0)" ::: "memory");

      // O += P V ; l += P . 1  (V^T in LDS, swizzled like K)
#pragma unroll
      for (int kk = 0; kk < 2; ++kk) {
        const bf16x8 ap = *(const bf16x8*)&Ps[w][l15 * 72 + kk * 32 + q4 * 8];
        lacc = __builtin_amdgcn_mfma_f32_16x16x32_bf16(ap, ones, lacc, 0, 0, 0);
#pragma unroll
        for (int di = 0; di < 4; ++di) {
          const bf16x8 bv =
              *(const bf16x8*)&Vts[cur][(di * 16 + l15) * 64 +
                                        (((kk * 4 + q4) ^ (l15 & 7)) << 3)];
          o[di] = __builtin_amdgcn_mfma_f32_16x16x32_bf16(ap, bv, o[di], 0, 0, 0);
        }
      }
    }

    const int row_base = (i * B_ + b) * L_ + qt * 64 + w * 16 + q4 * 4;
#pragma unroll
    for (int reg = 0; reg < 4; ++reg) {
      const float inv = 1.f / lacc[reg];
      const int r = row_base + reg;
#pragma unroll
      for (int di = 0; di < 4; ++di)
        attn[(size_t)r * E_ + h * 64 + di * 16 + l15] = (bf16_t)(o[di][reg] * inv);
    }
  }
}

// ---------------------------------------------------------------------------
// Combine: per (b,l) row: sum_i rmsnorm(a_i)*g_ln[i]*lw[i] + alpha*x, then
// final rmsnorm with g_final -> bf16 row (input to Wo GEMM).
// ---------------------------------------------------------------------------
__device__ __forceinline__ float block_sum(float v, float* sm)
{
#pragma unroll
  for (int off = 32; off > 0; off >>= 1) v += __shfl_xor(v, off);
  const int w = threadIdx.x >> 6;
  __syncthreads();
  if ((threadIdx.x & 63) == 0) sm[w] = v;
  __syncthreads();
  return sm[0] + sm[1] + sm[2] + sm[3];
}

__global__ __launch_bounds__(256) void combine_k(
    const bf16_t* __restrict__ attn, const float* __restrict__ x,
    const float* __restrict__ g_ln, const float* __restrict__ lambdas,
    const float* __restrict__ g_final, const float* __restrict__ alphap,
    bf16_t* __restrict__ xn)
{
  __shared__ float sm[4];
  const int row = blockIdx.x;
  const int tid = threadIdx.x;

  // lambda weights: sigmoid -> non-affine LayerNorm over NL=3
  float sg[3], lw[3];
#pragma unroll
  for (int i = 0; i < 3; ++i) sg[i] = 1.f / (1.f + expf(-lambdas[i]));
  const float mean = (sg[0] + sg[1] + sg[2]) * (1.f / 3.f);
  const float var = ((sg[0] - mean) * (sg[0] - mean) + (sg[1] - mean) * (sg[1] - mean) +
                     (sg[2] - mean) * (sg[2] - mean)) * (1.f / 3.f);
  const float rv = rsqrtf(var + 1e-5f);
#pragma unroll
  for (int i = 0; i < 3; ++i) lw[i] = (sg[i] - mean) * rv;

  const float av = alphap[0];
  float c[4];
#pragma unroll
  for (int k = 0; k < 4; ++k) {
    const int e = tid + k * 256;
    c[k] = av * x[(size_t)row * E_ + e];
  }

  for (int i = 0; i < 3; ++i) {
    float a[4];
    float ss = 0.f;
#pragma unroll
    for (int k = 0; k < 4; ++k) {
      const int e = tid + k * 256;
      a[k] = (float)attn[((size_t)i * (B_ * L_) + row) * E_ + e];
      ss += a[k] * a[k];
    }
    ss = block_sum(ss, sm);
    const float rinv = rsqrtf(ss * (1.f / (float)E_) + 1e-5f);
#pragma unroll
    for (int k = 0; k < 4; ++k) {
      const int e = tid + k * 256;
      c[k] += a[k] * rinv * g_ln[i * E_ + e] * lw[i];
    }
  }

  float ss = 0.f;
#pragma unroll
  for (int k = 0; k < 4; ++k) ss += c[k] * c[k];
  ss = block_sum(ss, sm);
  const float rinv = rsqrtf(ss * (1.f / (float)E_) + 1e-5f);
#pragma unroll
  for (int k = 0; k < 4; ++k) {
    const int e = tid + k * 256;
    xn[(size_t)row * E_ + e] = (bf16_t)(c[k] * rinv * g_final[e]);
  }
}

// ---------------------------------------------------------------------------
extern "C" void kernel_launch(void* const* d_in, const int* in_sizes, int n_in,
                              void* d_out, int out_size, void* d_ws, size_t ws_size,
                              hipStream_t stream)
{
  const float* x       = (const float*)d_in[0];
  const float* cosb    = (const float*)d_in[1];
  const float* sinb    = (const float*)d_in[2];
  // d_in[3] attn_mask: unused (causal mask applied analytically)
  const float* Wq      = (const float*)d_in[4];
  const float* Wk      = (const float*)d_in[5];
  const float* Wv      = (const float*)d_in[6];
  const float* g_ln    = (const float*)d_in[7];
  const float* lambdas = (const float*)d_in[8];
  const float* Wo      = (const float*)d_in[9];
  const float* g_final = (const float*)d_in[10];
  const float* alphap  = (const float*)d_in[11];

  // ws layout (bytes) — 75,497,472 total:
  //   qk    bf16 [6][B][H][L][D]  @ 0           25,165,824
  //   VT    bf16 [3][B][H][D][L]  @ 25,165,824  12,582,912
  //   attnb bf16 [3][B*L][E]      @ 37,748,736  12,582,912
  //   Wqkvb bf16 [3][NL][E][E]    @ 50,331,648  18,874,368
  //   Wob   bf16 [E][E]           @ 69,206,016   2,097,152
  //   xb    bf16 [B*L][E]         @ 71,303,168   4,194,304
  //   xnb   bf16 [B*L][E]         @ 0 (aliases dead qk)
  bf16_t* qk    = (bf16_t*)d_ws;
  bf16_t* VT    = (bf16_t*)((char*)d_ws + 25165824);
  bf16_t* attnb = (bf16_t*)((char*)d_ws + 37748736);
  bf16_t* Wqb   = (bf16_t*)((char*)d_ws + 50331648);
  bf16_t* Wkb   = Wqb + 3145728;
  bf16_t* Wvb   = Wkb + 3145728;
  bf16_t* Wob   = (bf16_t*)((char*)d_ws + 69206016);
  bf16_t* xb    = (bf16_t*)((char*)d_ws + 71303168);
  bf16_t* xnb   = (bf16_t*)d_ws;  // alias: qk dead after attn_k
  float*  out   = (float*)d_out;   // reference output dtype is float32

  // 0) fp32 -> bf16 conversion of weights + x
  cvt_k<<<dim3(3072, 5), 256, 0, stream>>>(Wq, Wk, Wv, Wo, x, Wqb, Wkb, Wvb, Wob, xb);
  // 1) QKV projections + rope / V-transpose: grid (16, 9 mats * 8 col-tiles)
  gemm_k<0><<<dim3(16, 72), 256, 0, stream>>>(xb, Wqb, Wkb, Wvb, cosb, sinb,
                                              qk, VT, nullptr);
  // 2) flash attention: grid (8 paired q-tiles, NL*B*H = 96)
  attn_k<<<dim3(8, 96), 256, 0, stream>>>(qk, VT, attnb);
  // 3) combine + final rmsnorm: one block per (b,l) row
  combine_k<<<dim3(B_ * L_), 256, 0, stream>>>(attnb, x, g_ln, lambdas, g_final,
                                               alphap, xnb);
  // 4) output projection @ Wo^T -> fp32 d_out
  gemm_k<1><<<dim3(16, 8), 256, 0, stream>>>(xnb, Wob, Wob, Wob, cosb, sinb,
                                             nullptr, nullptr, out);
}